// Round 3
// baseline (746.625 us; speedup 1.0000x reference)
//
#include <hip/hip_runtime.h>
#include <cstdint>
#include <cstddef>

typedef _Float16 half8 __attribute__((ext_vector_type(8)));
typedef _Float16 half4 __attribute__((ext_vector_type(4)));
typedef float floatx4 __attribute__((ext_vector_type(4)));

#define BATCH 256
#define NCHK 512
#define NVAR 1024
#define EDGE 3072

// ---- check MLP tiling ----
#define KC    96
#define NT1C  26     // hidden 388 -> 416 -> 26 col-tiles
#define SC_C  13     // 13 chunks of 32 hidden
#define NT2C  6      // out 96 -> 6 tiles
// ---- var MLP tiling ----
#define NT1V  13     // hidden 196 -> 208 -> 13 col-tiles
#define SC_V  7      // GEMM2 K padded 224 -> 7 chunks of 32
#define NT2V  4      // out 49 -> 64 -> 4 tiles

#define HSTR 40      // LDS chunk row stride in halves (80 B: 16B-aligned rows)

__device__ __forceinline__ float gelu_f(float x) {
  // exact gelu via A&S 7.1.26 erf approx, |err(erf)| < 1.5e-7
  float ax = fabsf(x) * 0.70710678118654752440f;
  float t  = 1.0f / (1.0f + 0.3275911f * ax);
  float p  = t * (0.254829592f + t * (-0.284496736f + t * (1.421413741f +
             t * (-1.453152027f + t * 1.061405429f))));
  float e  = __expf(-ax * ax);
  float erfv = 1.0f - p * e;
  float s  = (x >= 0.0f) ? erfv : -erfv;
  return 0.5f * x * (1.0f + s);
}

// Pack weights fp32->fp16 into MFMA fragment-major layout:
// frag[(s*NT + nt)*64 + lane][j] = W[k = s*32 + (lane>>4)*8 + j][n = nt*16 + (lane&15)]
// Also builds ipm = argsort(perm): ipm[perm[k]] = k.
__global__ void pack_kernel(const float* __restrict__ cW1, const float* __restrict__ cb1,
                            const float* __restrict__ cW2, const float* __restrict__ cb2,
                            const float* __restrict__ vW1, const float* __restrict__ vb1,
                            const float* __restrict__ vW2, const float* __restrict__ vb2,
                            const int* __restrict__ perm,
                            _Float16* __restrict__ w1c, _Float16* __restrict__ w2c,
                            _Float16* __restrict__ w1v, _Float16* __restrict__ w2v,
                            float* __restrict__ b1c, float* __restrict__ w96c,
                            float* __restrict__ b2c, float* __restrict__ b1v,
                            float* __restrict__ b2v, int* __restrict__ ipm)
{
  int id = blockIdx.x * 256 + threadIdx.x;
  const int S0 = 3 * NT1C * 64;      // 4992
  const int S1 = SC_C * NT2C * 64;   // 4992
  const int S2 = 2 * NT1V * 64;      // 1664
  const int S3 = SC_V * NT2V * 64;   // 1792
  if (id < S0) {
    int s = id / (NT1C * 64), rem = id % (NT1C * 64), nt = rem / 64, l = rem % 64;
    int q = l >> 4, n = nt * 16 + (l & 15);
    half8 v;
    #pragma unroll
    for (int j = 0; j < 8; ++j) {
      int k = s * 32 + q * 8 + j;
      float x = (n < 388) ? cW1[k * 388 + n] : 0.0f;
      v[j] = (_Float16)x;
    }
    *(half8*)(w1c + (size_t)id * 8) = v;
    return;
  }
  id -= S0;
  if (id < S1) {
    int s = id / (NT2C * 64), rem = id % (NT2C * 64), nt = rem / 64, l = rem % 64;
    int q = l >> 4, n = nt * 16 + (l & 15);
    half8 v;
    #pragma unroll
    for (int j = 0; j < 8; ++j) {
      int k = s * 32 + q * 8 + j;
      float x = (k < 388) ? cW2[k * 96 + n] : 0.0f;
      v[j] = (_Float16)x;
    }
    *(half8*)(w2c + (size_t)id * 8) = v;
    return;
  }
  id -= S1;
  if (id < S2) {
    int s = id / (NT1V * 64), rem = id % (NT1V * 64), nt = rem / 64, l = rem % 64;
    int q = l >> 4, n = nt * 16 + (l & 15);
    half8 v;
    #pragma unroll
    for (int j = 0; j < 8; ++j) {
      int k = s * 32 + q * 8 + j;                        // row 48 = prior row
      float x = (k < 49 && n < 196) ? vW1[k * 196 + n] : 0.0f;
      v[j] = (_Float16)x;
    }
    *(half8*)(w1v + (size_t)id * 8) = v;
    return;
  }
  id -= S2;
  if (id < S3) {
    int s = id / (NT2V * 64), rem = id % (NT2V * 64), nt = rem / 64, l = rem % 64;
    int q = l >> 4, n = nt * 16 + (l & 15);
    half8 v;
    #pragma unroll
    for (int j = 0; j < 8; ++j) {
      int k = s * 32 + q * 8 + j;
      float x = (k < 196 && n < 49) ? vW2[k * 49 + n] : 0.0f;
      v[j] = (_Float16)x;
    }
    *(half8*)(w2v + (size_t)id * 8) = v;
    return;
  }
  id -= S3;
  if (id < 416) { b1c[id]  = (id < 388) ? cb1[id] : 0.0f; return; }
  id -= 416;
  if (id < 416) { w96c[id] = (id < 388) ? cW1[96 * 388 + id] : 0.0f; return; }
  id -= 416;
  if (id < 96)  { b2c[id]  = cb2[id]; return; }
  id -= 96;
  if (id < 208) { b1v[id]  = (id < 196) ? vb1[id] : 0.0f; return; }
  id -= 208;
  if (id < 64)  { b2v[id]  = (id < 49) ? vb2[id] : 0.0f; return; }
  id -= 64;
  if (id < EDGE) { ipm[perm[id]] = id; return; }
}

// Check-node MLP, 32 rows/wave, transposed GEMMs.
// first!=0: synthesize Mc0 (channel 0 = prior[ipm[e]/3]) instead of reading Mc.
// Output scattered via ipm into variable-ordered Ycv so kernelV reads contiguous.
__global__ __launch_bounds__(256, 4) void kernelC(
    const _Float16* __restrict__ Mc, const int* __restrict__ synd,
    _Float16* __restrict__ Ycv,
    const _Float16* __restrict__ W1p, const _Float16* __restrict__ W2p,
    const float* __restrict__ b1, const float* __restrict__ w96,
    const float* __restrict__ b2, const int* __restrict__ ipm,
    const float* __restrict__ prior, int first)
{
  __shared__ _Float16 HL[4][32 * HSTR];   // 10 KiB
  const int tid = threadIdx.x, w = tid >> 6, l = tid & 63;
  const int q = l >> 4, c = l & 15;
  const int r0 = blockIdx.x * 128 + w * 32;

  half8 mb[2][3];
  float sg[2];
  #pragma unroll
  for (int rg = 0; rg < 2; ++rg) {
    const int row = r0 + rg * 16 + c;
    sg[rg] = 1.0f - 2.0f * (float)synd[row];
    if (first) {
      const int chk = row & (NCHK - 1);
      #pragma unroll
      for (int ks = 0; ks < 3; ++ks) {
        half8 m = {0,0,0,0,0,0,0,0};
        if ((q & 1) == 0)
          m[0] = (_Float16)prior[ipm[chk * 6 + ks * 2 + (q >> 1)] / 3];
        mb[rg][ks] = m;
      }
    } else {
      const _Float16* Arow = Mc + (size_t)row * KC;
      #pragma unroll
      for (int ks = 0; ks < 3; ++ks)
        mb[rg][ks] = *(const half8*)(Arow + ks * 32 + q * 8);
    }
  }

  floatx4 acc2[2][6];
  #pragma unroll
  for (int nt = 0; nt < 6; ++nt) {
    floatx4 bia = *(const floatx4*)(b2 + nt * 16 + q * 4);
    acc2[0][nt] = bia;
    acc2[1][nt] = bia;
  }

  const half8* W1f = (const half8*)W1p;
  const half8* W2f = (const half8*)W2p;
  _Float16* Hb = &HL[w][0];

  #pragma unroll 2
  for (int s = 0; s < SC_C; ++s) {
    #pragma unroll
    for (int u = 0; u < 2; ++u) {
      const int nt = s * 2 + u;
      half8 wa0 = W1f[(0 * NT1C + nt) * 64 + l];
      half8 wa1 = W1f[(1 * NT1C + nt) * 64 + l];
      half8 wa2 = W1f[(2 * NT1C + nt) * 64 + l];
      floatx4 bia = *(const floatx4*)(b1  + nt * 16 + q * 4);
      floatx4 wsg = *(const floatx4*)(w96 + nt * 16 + q * 4);
      #pragma unroll
      for (int rg = 0; rg < 2; ++rg) {
        floatx4 a;
        #pragma unroll
        for (int r = 0; r < 4; ++r) a[r] = bia[r] + sg[rg] * wsg[r];
        a = __builtin_amdgcn_mfma_f32_16x16x32_f16(wa0, mb[rg][0], a, 0, 0, 0);
        a = __builtin_amdgcn_mfma_f32_16x16x32_f16(wa1, mb[rg][1], a, 0, 0, 0);
        a = __builtin_amdgcn_mfma_f32_16x16x32_f16(wa2, mb[rg][2], a, 0, 0, 0);
        half4 hh;
        #pragma unroll
        for (int r = 0; r < 4; ++r)
          hh[r] = (_Float16)gelu_f(a[r]);
        *(half4*)(Hb + (rg * 16 + c) * HSTR + u * 16 + q * 4) = hh;
      }
    }
    half8 hf0 = *(const half8*)(Hb + (c)      * HSTR + q * 8);
    half8 hf1 = *(const half8*)(Hb + (16 + c) * HSTR + q * 8);
    #pragma unroll
    for (int nt = 0; nt < 6; ++nt) {
      half8 wb = W2f[(s * NT2C + nt) * 64 + l];
      acc2[0][nt] = __builtin_amdgcn_mfma_f32_16x16x32_f16(wb, hf0, acc2[0][nt], 0, 0, 0);
      acc2[1][nt] = __builtin_amdgcn_mfma_f32_16x16x32_f16(wb, hf1, acc2[1][nt], 0, 0, 0);
    }
  }

  #pragma unroll
  for (int rg = 0; rg < 2; ++rg) {
    const int row = r0 + rg * 16 + c;
    const int chk = row & (NCHK - 1);
    const size_t bb = (size_t)(row >> 9) * EDGE;
    #pragma unroll
    for (int nt = 0; nt < 6; ++nt) {
      const int ip = ipm[chk * 6 + nt];
      half4 yy;
      #pragma unroll
      for (int r = 0; r < 4; ++r)
        yy[r] = (_Float16)(acc2[rg][nt][r] * sg[rg]);
      *(half4*)(Ycv + (bb + ip) * 16 + q * 4) = yy;
    }
  }
}

// Variable-node MLP, 32 rows/wave. Reads Ycv contiguously (var-order, 48 halves
// per row + prior), scatters Mc via perm, emits llr.
__global__ __launch_bounds__(256, 4) void kernelV(
    const _Float16* __restrict__ Ycv, const int* __restrict__ perm,
    const float* __restrict__ prior,
    _Float16* __restrict__ Mc, float* __restrict__ outp,
    const _Float16* __restrict__ W1p, const _Float16* __restrict__ W2p,
    const float* __restrict__ b1, const float* __restrict__ b2)
{
  __shared__ _Float16 HL[4][32 * HSTR];
  const int tid = threadIdx.x, w = tid >> 6, l = tid & 63;
  const int q = l >> 4, c = l & 15;
  const int r0 = blockIdx.x * 128 + w * 32;
  const size_t yb = (size_t)(r0 >> 10) * EDGE;
  const int v0 = r0 & 1023;

  half8 mb[2][2];
  #pragma unroll
  for (int rg = 0; rg < 2; ++rg) {
    const int row = r0 + rg * 16 + c;
    const _Float16* Xr = Ycv + (size_t)row * 48;
    mb[rg][0] = *(const half8*)(Xr + q * 8);
    half8 m1 = {0,0,0,0,0,0,0,0};
    if (q < 2) m1 = *(const half8*)(Xr + 32 + q * 8);
    else if (q == 2) m1[0] = (_Float16)prior[row & 1023];
    mb[rg][1] = m1;
  }

  floatx4 acc2[2][4];
  #pragma unroll
  for (int nt = 0; nt < 4; ++nt) {
    floatx4 bia = *(const floatx4*)(b2 + nt * 16 + q * 4);
    acc2[0][nt] = bia;
    acc2[1][nt] = bia;
  }

  const half8* W1f = (const half8*)W1p;
  const half8* W2f = (const half8*)W2p;
  _Float16* Hb = &HL[w][0];

  #pragma unroll 2
  for (int s = 0; s < SC_V; ++s) {
    #pragma unroll
    for (int u = 0; u < 2; ++u) {
      const int nt = s * 2 + u;
      if (nt < NT1V) {
        half8 wa0 = W1f[(0 * NT1V + nt) * 64 + l];
        half8 wa1 = W1f[(1 * NT1V + nt) * 64 + l];
        floatx4 bia = *(const floatx4*)(b1 + nt * 16 + q * 4);
        #pragma unroll
        for (int rg = 0; rg < 2; ++rg) {
          floatx4 a = bia;
          a = __builtin_amdgcn_mfma_f32_16x16x32_f16(wa0, mb[rg][0], a, 0, 0, 0);
          a = __builtin_amdgcn_mfma_f32_16x16x32_f16(wa1, mb[rg][1], a, 0, 0, 0);
          half4 hh;
          #pragma unroll
          for (int r = 0; r < 4; ++r)
            hh[r] = (_Float16)gelu_f(a[r]);
          *(half4*)(Hb + (rg * 16 + c) * HSTR + u * 16 + q * 4) = hh;
        }
      } else {
        half4 hz = {0,0,0,0};
        #pragma unroll
        for (int rg = 0; rg < 2; ++rg)
          *(half4*)(Hb + (rg * 16 + c) * HSTR + u * 16 + q * 4) = hz;
      }
    }
    half8 hf0 = *(const half8*)(Hb + (c)      * HSTR + q * 8);
    half8 hf1 = *(const half8*)(Hb + (16 + c) * HSTR + q * 8);
    #pragma unroll
    for (int nt = 0; nt < 4; ++nt) {
      half8 wb = W2f[(s * NT2V + nt) * 64 + l];
      acc2[0][nt] = __builtin_amdgcn_mfma_f32_16x16x32_f16(wb, hf0, acc2[0][nt], 0, 0, 0);
      acc2[1][nt] = __builtin_amdgcn_mfma_f32_16x16x32_f16(wb, hf1, acc2[1][nt], 0, 0, 0);
    }
  }

  #pragma unroll
  for (int rg = 0; rg < 2; ++rg) {
    const int row = r0 + rg * 16 + c;
    const int v = v0 + rg * 16 + c;
    #pragma unroll
    for (int nt = 0; nt < 3; ++nt) {
      const int pe = perm[3 * v + nt];
      half4 yy;
      #pragma unroll
      for (int r = 0; r < 4; ++r)
        yy[r] = (_Float16)acc2[rg][nt][r];
      *(half4*)(Mc + (yb + pe) * 16 + q * 4) = yy;
    }
    if (q == 0)
      outp[row] = acc2[rg][3][0];   // b2[48] folded into acc init
  }
}

extern "C" void kernel_launch(void* const* d_in, const int* in_sizes, int n_in,
                              void* d_out, int out_size, void* d_ws, size_t ws_size,
                              hipStream_t stream)
{
  const int*   synd  = (const int*)d_in[0];
  const float* prior = (const float*)d_in[2];
  const int*   perm  = (const int*)d_in[3];
  const float* cW1 = (const float*)d_in[4];
  const float* cb1 = (const float*)d_in[5];
  const float* cW2 = (const float*)d_in[6];
  const float* cb2 = (const float*)d_in[7];
  const float* vW1 = (const float*)d_in[8];
  const float* vb1 = (const float*)d_in[9];
  const float* vW2 = (const float*)d_in[10];
  const float* vb2 = (const float*)d_in[11];
  float* outp = (float*)d_out;
  const int T = out_size / (BATCH * NVAR);

  char* p = (char*)d_ws;
  _Float16* Mc  = (_Float16*)p; p += (size_t)BATCH * EDGE * 16 * 2;
  _Float16* Ycv = (_Float16*)p; p += (size_t)BATCH * EDGE * 16 * 2;
  _Float16* w1c = (_Float16*)p; p += (size_t)3 * NT1C * 64 * 8 * 2;
  _Float16* w2c = (_Float16*)p; p += (size_t)SC_C * NT2C * 64 * 8 * 2;
  _Float16* w1v = (_Float16*)p; p += (size_t)2 * NT1V * 64 * 8 * 2;
  _Float16* w2v = (_Float16*)p; p += (size_t)SC_V * NT2V * 64 * 8 * 2;
  float* b1c  = (float*)p; p += 416 * 4;
  float* w96c = (float*)p; p += 416 * 4;
  float* b2c  = (float*)p; p += 96 * 4;
  float* b1v  = (float*)p; p += 208 * 4;
  float* b2v  = (float*)p; p += 64 * 4;
  int*   ipm  = (int*)p;   p += EDGE * 4;

  pack_kernel<<<(17712 + 255) / 256, 256, 0, stream>>>(
      cW1, cb1, cW2, cb2, vW1, vb1, vW2, vb2, perm,
      w1c, w2c, w1v, w2v, b1c, w96c, b2c, b1v, b2v, ipm);

  for (int t = 0; t < T; ++t) {
    kernelC<<<(BATCH * NCHK) / 128, 256, 0, stream>>>(
        Mc, synd, Ycv, w1c, w2c, b1c, w96c, b2c, ipm, prior, (t == 0) ? 1 : 0);
    kernelV<<<(BATCH * NVAR) / 128, 256, 0, stream>>>(
        Ycv, perm, prior, Mc, outp + (size_t)t * BATCH * NVAR, w1v, w2v, b1v, b2v);
  }
}